// Round 3
// baseline (261.556 us; speedup 1.0000x reference)
//
#include <hip/hip_runtime.h>
#include <hip/hip_bf16.h>

typedef unsigned short u16;
typedef __attribute__((ext_vector_type(8))) short short8;
typedef __attribute__((ext_vector_type(4))) float f32x4;

#define BATCH_ 32

static __device__ __forceinline__ float b2f(u16 u) {
  union { unsigned int i; float f; } v; v.i = ((unsigned int)u) << 16; return v.f;
}
static __device__ __forceinline__ u16 f2b(float x) {
  unsigned int i = __float_as_uint(x);
  unsigned int r = (i + 0x7fffu + ((i >> 16) & 1u)) >> 16;
  return (u16)r;
}

#define GCAST(p) ((const __attribute__((address_space(1))) void*)(p))
#define LCAST(p) ((__attribute__((address_space(3))) void*)(p))

// ---- elementwise f32 -> bf16 (n % 4 == 0)
__global__ __launch_bounds__(256) void cvt_bf16(const float* __restrict__ src,
                                                u16* __restrict__ dst, int n) {
  int i = (blockIdx.x * 256 + threadIdx.x) * 4;
  if (i >= n) return;
  float4 v = *(const float4*)(src + i);
  ushort4 o;
  o.x = f2b(v.x); o.y = f2b(v.y); o.z = f2b(v.z); o.w = f2b(v.w);
  *(ushort4*)(dst + i) = o;
}

// ---- transpose f32 [R][C] -> bf16 [C][R]
__global__ __launch_bounds__(256) void transpose_cvt(const float* __restrict__ src,
                                                     u16* __restrict__ dst, int R, int C) {
  __shared__ float tile[32][33];
  int c0 = blockIdx.x * 32, r0 = blockIdx.y * 32;
  int tx = threadIdx.x & 31, ty = threadIdx.x >> 5;
  #pragma unroll
  for (int i = 0; i < 32; i += 8)
    tile[ty + i][tx] = src[(long long)(r0 + ty + i) * C + c0 + tx];
  __syncthreads();
  #pragma unroll
  for (int i = 0; i < 32; i += 8)
    dst[(long long)(c0 + ty + i) * R + r0 + tx] = f2b(tile[tx][ty + i]);
}

// ---- scaled[b][k][o] = otherT[k][o] * fix[b][o]   (bf16)
__global__ __launch_bounds__(256) void build_scaled(const u16* __restrict__ oT,
                                                    const float* __restrict__ fix,
                                                    u16* __restrict__ out) {
  long long i4 = (long long)blockIdx.x * 256 + threadIdx.x; // group of 4 along o
  int o = (int)(i4 & 511) * 4;
  long long bk = i4 >> 9;            // b*512 + kk
  int b = (int)(bk >> 9);
  int kk = (int)(bk & 511);
  ushort4 v = *(const ushort4*)(oT + (long long)kk * 2048 + o);
  float4 f = *(const float4*)(fix + (long long)b * 2048 + o);
  ushort4 r;
  r.x = f2b(b2f(v.x) * f.x); r.y = f2b(b2f(v.y) * f.y);
  r.z = f2b(b2f(v.z) * f.z); r.w = f2b(b2f(v.w) * f.w);
  *(ushort4*)(out + bk * 2048 + o) = r;
}

// ---- masked row softmax: P[row][:] = softmax(S[row][:] * 1/sqrt(512), mask)
__global__ __launch_bounds__(256) void softmax_mask(const float* __restrict__ S,
                                                    const int* __restrict__ mask,
                                                    u16* __restrict__ P, int N) {
  const float scale = 0.044194173824159216f; // 1/sqrt(512)
  int row = blockIdx.x;
  int t = threadIdx.x;
  long long base = (long long)row * N;
  float vals[8]; int msk[8];
  float mx = -3.0e38f;
  #pragma unroll
  for (int i = 0; i < 8; ++i) {
    int c = t + i * 256;
    float s = S[base + c] * scale;
    int m = mask[base + c];
    vals[i] = s; msk[i] = m;
    if (!m) mx = fmaxf(mx, s);
  }
  #pragma unroll
  for (int off = 32; off; off >>= 1) mx = fmaxf(mx, __shfl_xor(mx, off));
  __shared__ float sred[4];
  if ((t & 63) == 0) sred[t >> 6] = mx;
  __syncthreads();
  mx = fmaxf(fmaxf(sred[0], sred[1]), fmaxf(sred[2], sred[3]));
  __syncthreads();
  float e[8]; float sum = 0.f;
  #pragma unroll
  for (int i = 0; i < 8; ++i) {
    e[i] = msk[i] ? 0.f : __expf(vals[i] - mx);
    sum += e[i];
  }
  #pragma unroll
  for (int off = 32; off; off >>= 1) sum += __shfl_xor(sum, off);
  if ((t & 63) == 0) sred[t >> 6] = sum;
  __syncthreads();
  sum = sred[0] + sred[1] + sred[2] + sred[3];
  float inv = (sum > 0.f) ? (1.f / sum) : 0.f;
  #pragma unroll
  for (int i = 0; i < 8; ++i) {
    int c = t + i * 256;
    P[base + c] = f2b(e[i] * inv);
  }
}

// ========== m97-exact GEMM: 128x128 tile, BK=64, global_load_lds(16B) =======
// C[m][n] = sum_k A[m][k] * Bt[n][k]   (both row-major, contraction on inner)
// EPI 0: outB = bf16(C + bias[col]); dual-weight via second half of grid.y
// EPI 1: outF = C (f32)
// EPI 2: col -> (b = col>>9, k = col&511); outF[b*M*512 + row*512 + k] = C
#define GBM 128
#define GBN 128
#define GBK 64

template<int EPI>
__global__ __launch_bounds__(256) void gemm_lds(
    const u16* __restrict__ A, const u16* __restrict__ Bt,
    const float* __restrict__ bias,
    const u16* __restrict__ Bt2, const float* __restrict__ bias2,
    float* __restrict__ outF, u16* __restrict__ outB,
    int M, int N, int K) {
  __shared__ u16 sA[GBM * GBK];   // 16 KB
  __shared__ u16 sB[GBN * GBK];   // 16 KB

  // T1: bijective XCD-chunked block swizzle (all grids have nwg % 8 == 0)
  int nwg = gridDim.x * gridDim.y;
  int wg = blockIdx.y * gridDim.x + blockIdx.x;
  int cpx = nwg >> 3;
  int swz = (wg & 7) * cpx + (wg >> 3);
  int bx = swz % gridDim.x, by = swz / gridDim.x;

  int m0 = by * GBM, n0 = bx * GBN;
  if (EPI == 0) {
    if (2 * by >= gridDim.y) { Bt = Bt2; bias = bias2; }
  }
  int t = threadIdx.x;
  int wid = t >> 6, lane = t & 63;
  int wm = (wid >> 1) * 64, wn = (wid & 1) * 64;
  int lr = lane & 15, lq = lane >> 4;
  int srow = lane >> 3;            // 0..7
  int schunk = (lane & 7) * 8;     // u16 offset within 128B row

  f32x4 acc[4][4];
  #pragma unroll
  for (int i = 0; i < 4; ++i)
    #pragma unroll
    for (int j = 0; j < 4; ++j)
      acc[i][j] = (f32x4){0.f, 0.f, 0.f, 0.f};

  // staging: wave wid owns rows [wid*32, wid*32+32); each gload stages 8 rows
  const u16* gA = A + (long long)(m0 + wid * 32 + srow) * K + schunk;
  const u16* gB = Bt + (long long)(n0 + wid * 32 + srow) * K + schunk;
  u16* lA = &sA[(wid * 32) * GBK];
  u16* lB = &sB[(wid * 32) * GBK];
  const long long rs = (long long)8 * K;   // 8-row global skip (u16)

  for (int k0 = 0; k0 < K; k0 += GBK) {
    #pragma unroll
    for (int g = 0; g < 4; ++g) {
      __builtin_amdgcn_global_load_lds(GCAST(gA + k0 + g * rs), LCAST(lA + g * 8 * GBK), 16, 0, 0);
      __builtin_amdgcn_global_load_lds(GCAST(gB + k0 + g * rs), LCAST(lB + g * 8 * GBK), 16, 0, 0);
    }
    __syncthreads();
    #pragma unroll
    for (int h = 0; h < 2; ++h) {
      short8 af[4], bf[4];
      #pragma unroll
      for (int i = 0; i < 4; ++i)
        af[i] = *(const short8*)&sA[(wm + i * 16 + lr) * GBK + h * 32 + lq * 8];
      #pragma unroll
      for (int j = 0; j < 4; ++j)
        bf[j] = *(const short8*)&sB[(wn + j * 16 + lr) * GBK + h * 32 + lq * 8];
      #pragma unroll
      for (int i = 0; i < 4; ++i)
        #pragma unroll
        for (int j = 0; j < 4; ++j)
          acc[i][j] = __builtin_amdgcn_mfma_f32_16x16x32_bf16(af[i], bf[j], acc[i][j], 0, 0, 0);
    }
    __syncthreads();
  }

  #pragma unroll
  for (int i = 0; i < 4; ++i) {
    #pragma unroll
    for (int j = 0; j < 4; ++j) {
      int col = n0 + wn + j * 16 + lr;
      #pragma unroll
      for (int r = 0; r < 4; ++r) {
        int row = m0 + wm + i * 16 + lq * 4 + r;
        float v = acc[i][j][r];
        if (EPI == 0) {
          outB[(long long)row * N + col] = f2b(v + bias[col]);
        } else if (EPI == 1) {
          outF[(long long)row * N + col] = v;
        } else {
          int b = col >> 9, kc = col & 511;
          outF[(long long)b * ((long long)M * 512) + (long long)row * 512 + kc] = v;
        }
      }
    }
  }
}

// ============ fallback (round-1 kernel) for small-ws path ============
#define BMT 128
#define BNT 128
#define BKT 32
#define LDSP 40

template<int MODE>
__global__ __launch_bounds__(256) void gemm_bt(
    const u16* __restrict__ A, const u16* __restrict__ Bt,
    const float* __restrict__ bias, const float* __restrict__ fixmat,
    float* __restrict__ outF, u16* __restrict__ outB,
    int M, int N, int K, long long out_batch_stride, int bt_batch_stride) {
  __shared__ u16 sA[BMT][LDSP];
  __shared__ u16 sB[BNT][LDSP];
  int b = blockIdx.z;
  const u16* Bt_b = Bt + (long long)b * bt_batch_stride;
  const float* fixrow = (MODE == 2) ? (fixmat + (long long)b * K) : nullptr;
  float* out_b = (MODE != 0) ? (outF + (long long)b * out_batch_stride) : nullptr;

  int m0 = blockIdx.y * BMT, n0 = blockIdx.x * BNT;
  int t = threadIdx.x;
  int wid = t >> 6, lane = t & 63;
  int wm = (wid >> 1) * 64, wn = (wid & 1) * 64;
  int lr = lane & 15, lq = lane >> 4;

  f32x4 acc[4][4];
  #pragma unroll
  for (int i = 0; i < 4; ++i)
    #pragma unroll
    for (int j = 0; j < 4; ++j)
      acc[i][j] = (f32x4){0.f, 0.f, 0.f, 0.f};

  int srow = t >> 1, scg = (t & 1) * 16;

  for (int k0 = 0; k0 < K; k0 += BKT) {
    {
      const u16* src = A + (long long)(m0 + srow) * K + k0 + scg;
      short8 v0 = *(const short8*)(src);
      short8 v1 = *(const short8*)(src + 8);
      *(short8*)&sA[srow][scg] = v0;
      *(short8*)&sA[srow][scg + 8] = v1;
    }
    {
      const u16* src = Bt_b + (long long)(n0 + srow) * K + k0 + scg;
      short8 v0 = *(const short8*)(src);
      short8 v1 = *(const short8*)(src + 8);
      if (MODE == 2) {
        u16* p0 = (u16*)&v0; u16* p1 = (u16*)&v1;
        #pragma unroll
        for (int j = 0; j < 8; ++j) {
          p0[j] = f2b(b2f(p0[j]) * fixrow[k0 + scg + j]);
          p1[j] = f2b(b2f(p1[j]) * fixrow[k0 + scg + 8 + j]);
        }
      }
      *(short8*)&sB[srow][scg] = v0;
      *(short8*)&sB[srow][scg + 8] = v1;
    }
    __syncthreads();
    short8 af[4], bf[4];
    #pragma unroll
    for (int i = 0; i < 4; ++i)
      af[i] = *(const short8*)&sA[wm + i * 16 + lr][lq * 8];
    #pragma unroll
    for (int j = 0; j < 4; ++j)
      bf[j] = *(const short8*)&sB[wn + j * 16 + lr][lq * 8];
    #pragma unroll
    for (int i = 0; i < 4; ++i)
      #pragma unroll
      for (int j = 0; j < 4; ++j)
        acc[i][j] = __builtin_amdgcn_mfma_f32_16x16x32_bf16(af[i], bf[j], acc[i][j], 0, 0, 0);
    __syncthreads();
  }

  #pragma unroll
  for (int i = 0; i < 4; ++i) {
    #pragma unroll
    for (int j = 0; j < 4; ++j) {
      int col = n0 + wn + j * 16 + lr;
      #pragma unroll
      for (int r = 0; r < 4; ++r) {
        int row = m0 + wm + i * 16 + lq * 4 + r;
        float v = acc[i][j][r];
        if (MODE == 0) {
          v += bias[col];
          outB[(long long)row * N + col] = f2b(v);
        } else {
          out_b[(long long)row * N + col] = v;
        }
      }
    }
  }
}

extern "C" void kernel_launch(void* const* d_in, const int* in_sizes, int n_in,
                              void* d_out, int out_size, void* d_ws, size_t ws_size,
                              hipStream_t stream) {
  const float* main_feat  = (const float*)d_in[0];
  const float* other_feat = (const float*)d_in[1];
  const float* fix_feat   = (const float*)d_in[2];
  const int*   mask       = (const int*)d_in[3];
  const float* Wq         = (const float*)d_in[4];
  const float* bq         = (const float*)d_in[5];
  const float* Wk         = (const float*)d_in[6];
  const float* bk         = (const float*)d_in[7];
  float* out = (float*)d_out;

  char* ws = (char*)d_ws;
  const size_t OFF_MAINB  = 0;          // 2 MiB  (mainB and otherB contiguous!)
  const size_t OFF_OTHERB = 2097152;    // 2 MiB
  const size_t OFF_WQB    = 4194304;    // 512 KiB
  const size_t OFF_WKB    = 4718592;    // 512 KiB
  const size_t OFF_QB     = 5242880;    // 2 MiB  (QB and KB contiguous!)
  const size_t OFF_KB     = 7340032;    // 2 MiB
  const size_t OFF_OTB    = 9437184;    // 2 MiB  (otherT bf16 [512][2048])
  const size_t OFF_P      = 11534336;   // 8 MiB  (P bf16 [2048][2048])
  const size_t OFF_S      = 19922944;   // 16 MiB (S f32 [2048][2048])
  const size_t OFF_SCALED = 36700160;   // 64 MiB (scaled bf16 [32][512][2048])
  const size_t NEED_SCALED = OFF_SCALED + (size_t)BATCH_ * 512 * 2048 * 2;

  u16* mainB  = (u16*)(ws + OFF_MAINB);
  u16* otherB = (u16*)(ws + OFF_OTHERB);
  u16* WqB    = (u16*)(ws + OFF_WQB);
  u16* WkB    = (u16*)(ws + OFF_WKB);
  u16* QB     = (u16*)(ws + OFF_QB);
  u16* KB     = (u16*)(ws + OFF_KB);
  u16* oTB    = (u16*)(ws + OFF_OTB);
  u16* P      = (u16*)(ws + OFF_P);
  float* S    = (float*)(ws + OFF_S);
  u16* scaled = (u16*)(ws + OFF_SCALED);
  bool use_scaled = (ws_size >= NEED_SCALED);

  // 1) bf16 conversions
  cvt_bf16<<<1024, 256, 0, stream>>>(main_feat, mainB, 2048 * 512);
  cvt_bf16<<<1024, 256, 0, stream>>>(other_feat, otherB, 2048 * 512);
  cvt_bf16<<<256, 256, 0, stream>>>(Wq, WqB, 512 * 512);
  cvt_bf16<<<256, 256, 0, stream>>>(Wk, WkB, 512 * 512);
  // 2) otherT bf16 [512][2048]
  transpose_cvt<<<dim3(16, 64), 256, 0, stream>>>(other_feat, oTB, 2048, 512);

  if (use_scaled) {
    // 3) fused Q|K projection: M=4096 (rows 0..2047 -> Wq/bq, 2048.. -> Wk/bk)
    gemm_lds<0><<<dim3(4, 32), 256, 0, stream>>>(mainB, WqB, bq, WkB, bk,
        nullptr, QB, 4096, 512, 512);
    // 4) S = Q @ K^T (f32, unscaled; softmax applies 1/sqrt(512))
    gemm_lds<1><<<dim3(16, 16), 256, 0, stream>>>(QB, KB, nullptr, nullptr, nullptr,
        S, nullptr, 2048, 2048, 512);
    // 5) masked softmax -> P bf16
    softmax_mask<<<2048, 256, 0, stream>>>(S, mask, P, 2048);
    // 6) scaled[b][k][o] = otherT[k][o]*fix[b][o], viewed as Bt [16384][2048]
    build_scaled<<<32768, 256, 0, stream>>>(oTB, fix_feat, scaled);
    // 7) single big GEMM: out2[m, b*512+k] with strided epilogue
    gemm_lds<2><<<dim3(128, 16), 256, 0, stream>>>(P, scaled, nullptr, nullptr, nullptr,
        out, nullptr, 2048, 16384, 2048);
  } else {
    // fallback: round-1 path (no 64MB scaled buffer)
    gemm_bt<0><<<dim3(4, 16, 1), 256, 0, stream>>>(mainB, WqB, bq, nullptr,
        nullptr, QB, 2048, 512, 512, 0, 0);
    gemm_bt<0><<<dim3(4, 16, 1), 256, 0, stream>>>(otherB, WkB, bk, nullptr,
        nullptr, KB, 2048, 512, 512, 0, 0);
    gemm_bt<1><<<dim3(16, 16, 1), 256, 0, stream>>>(QB, KB, nullptr, nullptr,
        S, nullptr, 2048, 2048, 512, 0, 0);
    softmax_mask<<<2048, 256, 0, stream>>>(S, mask, P, 2048);
    gemm_bt<2><<<dim3(4, 16, BATCH_), 256, 0, stream>>>(P, oTB, nullptr, fix_feat,
        out, nullptr, 2048, 512, 2048, 1048576LL, 0);
  }
}

// Round 4
// 196.247 us; speedup vs baseline: 1.3328x; 1.3328x over previous
//
#include <hip/hip_runtime.h>
#include <hip/hip_bf16.h>

typedef unsigned short u16;
typedef __attribute__((ext_vector_type(8))) short short8;
typedef __attribute__((ext_vector_type(4))) float f32x4;

#define BATCH_ 32

static __device__ __forceinline__ float b2f(u16 u) {
  union { unsigned int i; float f; } v; v.i = ((unsigned int)u) << 16; return v.f;
}
static __device__ __forceinline__ u16 f2b(float x) {
  unsigned int i = __float_as_uint(x);
  unsigned int r = (i + 0x7fffu + ((i >> 16) & 1u)) >> 16;
  return (u16)r;
}

#define GCAST(p) ((const __attribute__((address_space(1))) void*)(p))
#define LCAST(p) ((__attribute__((address_space(3))) void*)(p))

// ---- elementwise f32 -> bf16 (n % 4 == 0)
__global__ __launch_bounds__(256) void cvt_bf16(const float* __restrict__ src,
                                                u16* __restrict__ dst, int n) {
  int i = (blockIdx.x * 256 + threadIdx.x) * 4;
  if (i >= n) return;
  float4 v = *(const float4*)(src + i);
  ushort4 o;
  o.x = f2b(v.x); o.y = f2b(v.y); o.z = f2b(v.z); o.w = f2b(v.w);
  *(ushort4*)(dst + i) = o;
}

// ---- transpose f32 [R][C] -> bf16 [C][R]
__global__ __launch_bounds__(256) void transpose_cvt(const float* __restrict__ src,
                                                     u16* __restrict__ dst, int R, int C) {
  __shared__ float tile[32][33];
  int c0 = blockIdx.x * 32, r0 = blockIdx.y * 32;
  int tx = threadIdx.x & 31, ty = threadIdx.x >> 5;
  #pragma unroll
  for (int i = 0; i < 32; i += 8)
    tile[ty + i][tx] = src[(long long)(r0 + ty + i) * C + c0 + tx];
  __syncthreads();
  #pragma unroll
  for (int i = 0; i < 32; i += 8)
    dst[(long long)(c0 + ty + i) * R + r0 + tx] = f2b(tile[tx][ty + i]);
}

// ---- scaled[b][k][o] = otherT[k][o] * fix[b][o]   (bf16)
__global__ __launch_bounds__(256) void build_scaled(const u16* __restrict__ oT,
                                                    const float* __restrict__ fix,
                                                    u16* __restrict__ out) {
  long long i4 = (long long)blockIdx.x * 256 + threadIdx.x; // group of 4 along o
  int o = (int)(i4 & 511) * 4;
  long long bk = i4 >> 9;            // b*512 + kk
  int b = (int)(bk >> 9);
  int kk = (int)(bk & 511);
  ushort4 v = *(const ushort4*)(oT + (long long)kk * 2048 + o);
  float4 f = *(const float4*)(fix + (long long)b * 2048 + o);
  ushort4 r;
  r.x = f2b(b2f(v.x) * f.x); r.y = f2b(b2f(v.y) * f.y);
  r.z = f2b(b2f(v.z) * f.z); r.w = f2b(b2f(v.w) * f.w);
  *(ushort4*)(out + bk * 2048 + o) = r;
}

// ---- masked row softmax: P[row][:] = softmax(S[row][:] * 1/sqrt(512), mask)
__global__ __launch_bounds__(256) void softmax_mask(const float* __restrict__ S,
                                                    const int* __restrict__ mask,
                                                    u16* __restrict__ P, int N) {
  const float scale = 0.044194173824159216f; // 1/sqrt(512)
  int row = blockIdx.x;
  int t = threadIdx.x;
  long long base = (long long)row * N;
  float vals[8]; int msk[8];
  float mx = -3.0e38f;
  #pragma unroll
  for (int i = 0; i < 8; ++i) {
    int c = t + i * 256;
    float s = S[base + c] * scale;
    int m = mask[base + c];
    vals[i] = s; msk[i] = m;
    if (!m) mx = fmaxf(mx, s);
  }
  #pragma unroll
  for (int off = 32; off; off >>= 1) mx = fmaxf(mx, __shfl_xor(mx, off));
  __shared__ float sred[4];
  if ((t & 63) == 0) sred[t >> 6] = mx;
  __syncthreads();
  mx = fmaxf(fmaxf(sred[0], sred[1]), fmaxf(sred[2], sred[3]));
  __syncthreads();
  float e[8]; float sum = 0.f;
  #pragma unroll
  for (int i = 0; i < 8; ++i) {
    e[i] = msk[i] ? 0.f : __expf(vals[i] - mx);
    sum += e[i];
  }
  #pragma unroll
  for (int off = 32; off; off >>= 1) sum += __shfl_xor(sum, off);
  if ((t & 63) == 0) sred[t >> 6] = sum;
  __syncthreads();
  sum = sred[0] + sred[1] + sred[2] + sred[3];
  float inv = (sum > 0.f) ? (1.f / sum) : 0.f;
  #pragma unroll
  for (int i = 0; i < 8; ++i) {
    int c = t + i * 256;
    P[base + c] = f2b(e[i] * inv);
  }
}

// ========== r2-proven 128x128 / BK=32 GEMM (small GEMMs: Q|K proj, S) ======
// EPI 0: outB = bf16(C + bias[col]); dual-weight via second half of grid.y
// EPI 1: outF = C (f32)
#define GBM 128
#define GBN 128
#define GBK 32

template<int EPI>
__global__ __launch_bounds__(256) void gemm_lds(
    const u16* __restrict__ A, const u16* __restrict__ Bt,
    const float* __restrict__ bias,
    const u16* __restrict__ Bt2, const float* __restrict__ bias2,
    float* __restrict__ outF, u16* __restrict__ outB,
    int M, int N, int K) {
  __shared__ u16 sA[GBM * GBK];
  __shared__ u16 sB[GBN * GBK];
  int m0 = blockIdx.y * GBM, n0 = blockIdx.x * GBN;
  if (EPI == 0) {
    if (2 * blockIdx.y >= gridDim.y) { Bt = Bt2; bias = bias2; }
  }
  int t = threadIdx.x;
  int wid = t >> 6, lane = t & 63;
  int wm = (wid >> 1) * 64, wn = (wid & 1) * 64;
  int lr = lane & 15, lq = lane >> 4;
  int srow = lane >> 2, schunk = (lane & 3) * 8;

  f32x4 acc[4][4];
  #pragma unroll
  for (int i = 0; i < 4; ++i)
    #pragma unroll
    for (int j = 0; j < 4; ++j)
      acc[i][j] = (f32x4){0.f, 0.f, 0.f, 0.f};

  const u16* gA = A + (long long)(m0 + wid * 32 + srow) * K + schunk;
  const u16* gB = Bt + (long long)(n0 + wid * 32 + srow) * K + schunk;
  u16* lA = &sA[(wid * 32) * GBK];
  u16* lB = &sB[(wid * 32) * GBK];
  const long long rowskip = (long long)16 * K;

  for (int k0 = 0; k0 < K; k0 += GBK) {
    __builtin_amdgcn_global_load_lds(GCAST(gA + k0),           LCAST(lA),            16, 0, 0);
    __builtin_amdgcn_global_load_lds(GCAST(gA + k0 + rowskip), LCAST(lA + 16 * GBK), 16, 0, 0);
    __builtin_amdgcn_global_load_lds(GCAST(gB + k0),           LCAST(lB),            16, 0, 0);
    __builtin_amdgcn_global_load_lds(GCAST(gB + k0 + rowskip), LCAST(lB + 16 * GBK), 16, 0, 0);
    __syncthreads();
    short8 af[4], bf[4];
    #pragma unroll
    for (int i = 0; i < 4; ++i)
      af[i] = *(const short8*)&sA[(wm + i * 16 + lr) * GBK + lq * 8];
    #pragma unroll
    for (int j = 0; j < 4; ++j)
      bf[j] = *(const short8*)&sB[(wn + j * 16 + lr) * GBK + lq * 8];
    #pragma unroll
    for (int i = 0; i < 4; ++i)
      #pragma unroll
      for (int j = 0; j < 4; ++j)
        acc[i][j] = __builtin_amdgcn_mfma_f32_16x16x32_bf16(af[i], bf[j], acc[i][j], 0, 0, 0);
    __syncthreads();
  }

  #pragma unroll
  for (int i = 0; i < 4; ++i) {
    #pragma unroll
    for (int j = 0; j < 4; ++j) {
      int col = n0 + wn + j * 16 + lr;
      #pragma unroll
      for (int r = 0; r < 4; ++r) {
        int row = m0 + wm + i * 16 + lq * 4 + r;
        float v = acc[i][j][r];
        if (EPI == 0) {
          outB[(long long)row * N + col] = f2b(v + bias[col]);
        } else {
          outF[(long long)row * N + col] = v;
        }
      }
    }
  }
}

// ========== ring-4 counted-vmcnt 256x256 GEMM (the big batched PV GEMM) ====
// C[m][n] = sum_k A[m][k]*Bt[n][k]; epilogue scatters n -> (b=n>>9, k=n&511):
// outF[b*(M*512) + m*512 + kc] = C.
// 512 threads = 8 waves (2 Mx4 N). BK=32. LDS ring of 4 buffers (128 KiB).
// Iter kt: ds_read buf[kt&3]; stage tile kt+3 -> buf[(kt+3)&3] (= buf[(kt-1)&3],
// whose reads finished 2 barriers ago -> no W/R overlap); 32 MFMA; counted
// vmcnt (8 steady / 4 / 0 at tail); raw s_barrier (no vmcnt(0) drain).
// LDS chunk swizzle: chunk ^= (row&3) on read, inverse-applied on the global
// source address (global_load_lds dest stays linear). 8-way -> ~4-way.
__global__ __launch_bounds__(512, 2) void gemm_ring(
    const u16* __restrict__ A, const u16* __restrict__ Bt,
    float* __restrict__ outF, int M, int N, int K) {
  __shared__ u16 lds[4][2][8192];   // [ring][A/B][row*32 + chunk*8] = 128 KiB

  // block swizzle: grid = (M/256=8, N/256). XCD x owns a contiguous N-chunk,
  // M sweeps fastest inside -> each B-panel reused 8x within one XCD L2.
  int nwg = gridDim.x * gridDim.y;
  int wg = blockIdx.y * gridDim.x + blockIdx.x;
  int cpx = nwg >> 3;
  int swz = (wg & 7) * cpx + (wg >> 3);
  int bx = swz & 7, by = swz >> 3;          // gridDim.x == 8
  int m0 = bx * 256, n0 = by * 256;

  int t = threadIdx.x;
  int w = t >> 6, lane = t & 63;
  int wr = w >> 2, wc = w & 3;              // wave tile: 128 rows x 64 cols
  int lr = lane & 15, lq = lane >> 4;
  int csw = (lq ^ (lr & 3)) * 8;            // swizzled chunk offset (u16)

  // staging source (pre-swizzled): thread t covers row (t>>2), chunk (t&3)
  int srow = t >> 2;                         // 0..127
  int sgc = ((t & 3) ^ (srow & 3)) * 8;      // inverse-swizzled global chunk
  const u16* pA0 = A + (long long)(m0 + srow) * K + sgc;
  const u16* pA1 = pA0 + (long long)128 * K;
  const u16* pB0 = Bt + (long long)(n0 + srow) * K + sgc;
  const u16* pB1 = pB0 + (long long)128 * K;
  // wave-uniform LDS bases (lane*16B appended by HW)
  const int lbase = (w * 16) * 32;           // u16 index

  f32x4 acc[8][4];
  #pragma unroll
  for (int i = 0; i < 8; ++i)
    #pragma unroll
    for (int j = 0; j < 4; ++j)
      acc[i][j] = (f32x4){0.f, 0.f, 0.f, 0.f};

  const int NT = K >> 5;   // K/32 tiles

  #define STAGE_TILE(KT, SB)                                                          \
    do {                                                                              \
      long long cofs = (long long)(KT) * 32;                                          \
      __builtin_amdgcn_global_load_lds(GCAST(pA0 + cofs), LCAST(&lds[SB][0][lbase]),           16, 0, 0); \
      __builtin_amdgcn_global_load_lds(GCAST(pA1 + cofs), LCAST(&lds[SB][0][lbase + 128 * 32]), 16, 0, 0); \
      __builtin_amdgcn_global_load_lds(GCAST(pB0 + cofs), LCAST(&lds[SB][1][lbase]),           16, 0, 0); \
      __builtin_amdgcn_global_load_lds(GCAST(pB1 + cofs), LCAST(&lds[SB][1][lbase + 128 * 32]), 16, 0, 0); \
    } while (0)

  // prologue: stage tiles 0,1,2; wait tile0 (<=8 outstanding); barrier
  STAGE_TILE(0, 0);
  STAGE_TILE(1, 1);
  STAGE_TILE(2, 2);
  asm volatile("s_waitcnt vmcnt(8)" ::: "memory");
  __builtin_amdgcn_s_barrier();
  __builtin_amdgcn_sched_barrier(0);

  for (int kt = 0; kt < NT; ++kt) {
    const int buf = kt & 3;
    short8 af[8], bf[4];
    #pragma unroll
    for (int i = 0; i < 8; ++i)
      af[i] = *(const short8*)&lds[buf][0][(wr * 128 + i * 16 + lr) * 32 + csw];
    #pragma unroll
    for (int j = 0; j < 4; ++j)
      bf[j] = *(const short8*)&lds[buf][1][(wc * 64 + j * 16 + lr) * 32 + csw];

    if (kt + 3 < NT) STAGE_TILE(kt + 3, (kt + 3) & 3);

    __builtin_amdgcn_s_setprio(1);
    #pragma unroll
    for (int i = 0; i < 8; ++i)
      #pragma unroll
      for (int j = 0; j < 4; ++j)
        acc[i][j] = __builtin_amdgcn_mfma_f32_16x16x32_bf16(af[i], bf[j], acc[i][j], 0, 0, 0);
    __builtin_amdgcn_s_setprio(0);

    // counted wait: ensure tile kt+1 resident before next iter's reads
    if (kt + 3 < NT)       asm volatile("s_waitcnt vmcnt(8)" ::: "memory");
    else if (kt == NT - 3) asm volatile("s_waitcnt vmcnt(4)" ::: "memory");
    else if (kt == NT - 2) asm volatile("s_waitcnt vmcnt(0)" ::: "memory");
    __builtin_amdgcn_s_barrier();
    __builtin_amdgcn_sched_barrier(0);
  }
  #undef STAGE_TILE

  // epilogue: scatter cols -> per-batch layout
  #pragma unroll
  for (int i = 0; i < 8; ++i) {
    #pragma unroll
    for (int j = 0; j < 4; ++j) {
      int col = n0 + wc * 64 + j * 16 + lr;
      int b = col >> 9, kc = col & 511;
      float* ob = outF + (long long)b * ((long long)M * 512) + kc;
      #pragma unroll
      for (int r = 0; r < 4; ++r) {
        int row = m0 + wr * 128 + i * 16 + lq * 4 + r;
        ob[(long long)row * 512] = acc[i][j][r];
      }
    }
  }
}

// ============ fallback (round-1 kernel) for small-ws path ============
#define BMT 128
#define BNT 128
#define BKT 32
#define LDSP 40

template<int MODE>
__global__ __launch_bounds__(256) void gemm_bt(
    const u16* __restrict__ A, const u16* __restrict__ Bt,
    const float* __restrict__ bias, const float* __restrict__ fixmat,
    float* __restrict__ outF, u16* __restrict__ outB,
    int M, int N, int K, long long out_batch_stride, int bt_batch_stride) {
  __shared__ u16 sA[BMT][LDSP];
  __shared__ u16 sB[BNT][LDSP];
  int b = blockIdx.z;
  const u16* Bt_b = Bt + (long long)b * bt_batch_stride;
  const float* fixrow = (MODE == 2) ? (fixmat + (long long)b * K) : nullptr;
  float* out_b = (MODE != 0) ? (outF + (long long)b * out_batch_stride) : nullptr;

  int m0 = blockIdx.y * BMT, n0 = blockIdx.x * BNT;
  int t = threadIdx.x;
  int wid = t >> 6, lane = t & 63;
  int wm = (wid >> 1) * 64, wn = (wid & 1) * 64;
  int lr = lane & 15, lq = lane >> 4;

  f32x4 acc[4][4];
  #pragma unroll
  for (int i = 0; i < 4; ++i)
    #pragma unroll
    for (int j = 0; j < 4; ++j)
      acc[i][j] = (f32x4){0.f, 0.f, 0.f, 0.f};

  int srow = t >> 1, scg = (t & 1) * 16;

  for (int k0 = 0; k0 < K; k0 += BKT) {
    {
      const u16* src = A + (long long)(m0 + srow) * K + k0 + scg;
      short8 v0 = *(const short8*)(src);
      short8 v1 = *(const short8*)(src + 8);
      *(short8*)&sA[srow][scg] = v0;
      *(short8*)&sA[srow][scg + 8] = v1;
    }
    {
      const u16* src = Bt_b + (long long)(n0 + srow) * K + k0 + scg;
      short8 v0 = *(const short8*)(src);
      short8 v1 = *(const short8*)(src + 8);
      if (MODE == 2) {
        u16* p0 = (u16*)&v0; u16* p1 = (u16*)&v1;
        #pragma unroll
        for (int j = 0; j < 8; ++j) {
          p0[j] = f2b(b2f(p0[j]) * fixrow[k0 + scg + j]);
          p1[j] = f2b(b2f(p1[j]) * fixrow[k0 + scg + 8 + j]);
        }
      }
      *(short8*)&sB[srow][scg] = v0;
      *(short8*)&sB[srow][scg + 8] = v1;
    }
    __syncthreads();
    short8 af[4], bf[4];
    #pragma unroll
    for (int i = 0; i < 4; ++i)
      af[i] = *(const short8*)&sA[wm + i * 16 + lr][lq * 8];
    #pragma unroll
    for (int j = 0; j < 4; ++j)
      bf[j] = *(const short8*)&sB[wn + j * 16 + lr][lq * 8];
    #pragma unroll
    for (int i = 0; i < 4; ++i)
      #pragma unroll
      for (int j = 0; j < 4; ++j)
        acc[i][j] = __builtin_amdgcn_mfma_f32_16x16x32_bf16(af[i], bf[j], acc[i][j], 0, 0, 0);
    __syncthreads();
  }

  #pragma unroll
  for (int i = 0; i < 4; ++i) {
    #pragma unroll
    for (int j = 0; j < 4; ++j) {
      int col = n0 + wn + j * 16 + lr;
      #pragma unroll
      for (int r = 0; r < 4; ++r) {
        int row = m0 + wm + i * 16 + lq * 4 + r;
        float v = acc[i][j][r];
        if (MODE == 0) {
          v += bias[col];
          outB[(long long)row * N + col] = f2b(v);
        } else {
          out_b[(long long)row * N + col] = v;
        }
      }
    }
  }
}

extern "C" void kernel_launch(void* const* d_in, const int* in_sizes, int n_in,
                              void* d_out, int out_size, void* d_ws, size_t ws_size,
                              hipStream_t stream) {
  const float* main_feat  = (const float*)d_in[0];
  const float* other_feat = (const float*)d_in[1];
  const float* fix_feat   = (const float*)d_in[2];
  const int*   mask       = (const int*)d_in[3];
  const float* Wq         = (const float*)d_in[4];
  const float* bq         = (const float*)d_in[5];
  const float* Wk         = (const float*)d_in[6];
  const float* bk         = (const float*)d_in[7];
  float* out = (float*)d_out;

  char* ws = (char*)d_ws;
  const size_t OFF_MAINB  = 0;          // 2 MiB  (mainB and otherB contiguous!)
  const size_t OFF_OTHERB = 2097152;    // 2 MiB
  const size_t OFF_WQB    = 4194304;    // 512 KiB
  const size_t OFF_WKB    = 4718592;    // 512 KiB
  const size_t OFF_QB     = 5242880;    // 2 MiB  (QB and KB contiguous!)
  const size_t OFF_KB     = 7340032;    // 2 MiB
  const size_t OFF_OTB    = 9437184;    // 2 MiB  (otherT bf16 [512][2048])
  const size_t OFF_P      = 11534336;   // 8 MiB  (P bf16 [2048][2048])
  const size_t OFF_S      = 19922944;   // 16 MiB (S f32 [2048][2048])
  const size_t OFF_SCALED = 36700160;   // 64 MiB (scaled bf16 [32][512][2048])
  const size_t NEED_SCALED = OFF_SCALED + (size_t)BATCH_ * 512 * 2048 * 2;

  u16* mainB  = (u16*)(ws + OFF_MAINB);
  u16* otherB = (u16*)(ws + OFF_OTHERB);
  u16* WqB    = (u16*)(ws + OFF_WQB);
  u16* WkB    = (u16*)(ws + OFF_WKB);
  u16* QB     = (u16*)(ws + OFF_QB);
  u16* KB     = (u16*)(ws + OFF_KB);
  u16* oTB    = (u16*)(ws + OFF_OTB);
  u16* P      = (u16*)(ws + OFF_P);
  float* S    = (float*)(ws + OFF_S);
  u16* scaled = (u16*)(ws + OFF_SCALED);
  bool use_scaled = (ws_size >= NEED_SCALED);

  // 1) bf16 conversions
  cvt_bf16<<<1024, 256, 0, stream>>>(main_feat, mainB, 2048 * 512);
  cvt_bf16<<<1024, 256, 0, stream>>>(other_feat, otherB, 2048 * 512);
  cvt_bf16<<<256, 256, 0, stream>>>(Wq, WqB, 512 * 512);
  cvt_bf16<<<256, 256, 0, stream>>>(Wk, WkB, 512 * 512);
  // 2) otherT bf16 [512][2048]
  transpose_cvt<<<dim3(16, 64), 256, 0, stream>>>(other_feat, oTB, 2048, 512);

  if (use_scaled) {
    // 3) fused Q|K projection: M=4096 (rows 0..2047 -> Wq/bq, 2048.. -> Wk/bk)
    gemm_lds<0><<<dim3(4, 32), 256, 0, stream>>>(mainB, WqB, bq, WkB, bk,
        nullptr, QB, 4096, 512, 512);
    // 4) S = Q @ K^T (f32, unscaled; softmax applies 1/sqrt(512))
    gemm_lds<1><<<dim3(16, 16), 256, 0, stream>>>(QB, KB, nullptr, nullptr, nullptr,
        S, nullptr, 2048, 2048, 512);
    // 5) masked softmax -> P bf16
    softmax_mask<<<2048, 256, 0, stream>>>(S, mask, P, 2048);
    // 6) scaled[b][k][o] = otherT[k][o]*fix[b][o], viewed as Bt [16384][2048]
    build_scaled<<<32768, 256, 0, stream>>>(oTB, fix_feat, scaled);
    // 7) single big ring-pipelined GEMM: out[b][m][k] via col scatter
    gemm_ring<<<dim3(8, 64), 512, 0, stream>>>(P, scaled, out, 2048, 16384, 2048);
  } else {
    // fallback: round-1 path (no 64MB scaled buffer)
    gemm_bt<0><<<dim3(4, 16, 1), 256, 0, stream>>>(mainB, WqB, bq, nullptr,
        nullptr, QB, 2048, 512, 512, 0, 0);
    gemm_bt<0><<<dim3(4, 16, 1), 256, 0, stream>>>(otherB, WkB, bk, nullptr,
        nullptr, KB, 2048, 512, 512, 0, 0);
    gemm_bt<1><<<dim3(16, 16, 1), 256, 0, stream>>>(QB, KB, nullptr, nullptr,
        S, nullptr, 2048, 2048, 512, 0, 0);
    softmax_mask<<<2048, 256, 0, stream>>>(S, mask, P, 2048);
    gemm_bt<2><<<dim3(4, 16, BATCH_), 256, 0, stream>>>(P, oTB, nullptr, fix_feat,
        out, nullptr, 2048, 512, 2048, 1048576LL, 0);
  }
}